// Round 1
// 384.671 us; speedup vs baseline: 1.0375x; 1.0375x over previous
//
#include <hip/hip_runtime.h>

#define K_CODES 8192
#define D_DIM   512
#define N_ROWS  16384
#define NSPLIT  32          /* code splits of 256 */
#define CAP     8
#define T2      2.0e-4f     /* dot-space margin (validated r4-r6) */
#define LIST_CAP 32768

typedef __attribute__((ext_vector_type(8))) short bf16x8;
typedef __attribute__((ext_vector_type(4))) float f32x4;
typedef unsigned char uchar;
typedef unsigned short ushort;
typedef unsigned long long u64;

__device__ __forceinline__ unsigned fkey(float f) {
    unsigned b = __float_as_uint(f);
    return (b & 0x80000000u) ? ~b : (b | 0x80000000u);
}
__device__ __forceinline__ float finv(unsigned k) {
    return __uint_as_float((k & 0x80000000u) ? (k & 0x7fffffffu) : ~k);
}

__device__ __forceinline__ unsigned pk_bf16(float a, float b) {
    unsigned ua = __float_as_uint(a), ub = __float_as_uint(b);
    ua = (ua + 0x7fffu + ((ua >> 16) & 1u)) >> 16;
    ub = (ub + 0x7fffu + ((ub >> 16) & 1u)) & 0xffff0000u;
    return ua | ub;
}

// async global->LDS, 16B per lane; LDS dest = wave-uniform base + lane*16
__device__ __forceinline__ void gload_lds16(const void* g, void* l) {
    __builtin_amdgcn_global_load_lds(
        (const __attribute__((address_space(1))) unsigned int*)g,
        (__attribute__((address_space(3))) unsigned int*)l, 16, 0, 0);
}

// ---------------------------------------------------------------------------
// K0 (pre path): bf16 conversion of x/cb  +  fused exact ||z||^2 (numpy
// pairwise bit-exact, 32-lane parallel)  +  keys/count init.
// Blocks [0,6144): conversion; [6144,8192): sn+init.
// ---------------------------------------------------------------------------
__global__ void vq_prepass(const float* __restrict__ x, const float* __restrict__ cb,
                           unsigned* __restrict__ xb, unsigned* __restrict__ cbb,
                           float* __restrict__ sn, u64* __restrict__ keys,
                           int* __restrict__ count) {
    const int bid = blockIdx.x;
    const int t = threadIdx.x;
    if (bid < 6144) {
        const size_t gid = (size_t)bid * 256 + t;
        const size_t nx = (size_t)N_ROWS * D_DIM / 8;     // 1048576
        if (gid < nx) {
            const float4 f0 = ((const float4*)x)[gid * 2];
            const float4 f1 = ((const float4*)x)[gid * 2 + 1];
            ((uint4*)xb)[gid] = make_uint4(pk_bf16(f0.x, f0.y), pk_bf16(f0.z, f0.w),
                                           pk_bf16(f1.x, f1.y), pk_bf16(f1.z, f1.w));
        } else {
            const size_t g = gid - nx;
            const float4 f0 = ((const float4*)cb)[g * 2];
            const float4 f1 = ((const float4*)cb)[g * 2 + 1];
            ((uint4*)cbb)[g] = make_uint4(pk_bf16(f0.x, f0.y), pk_bf16(f0.z, f0.w),
                                          pk_bf16(f1.x, f1.y), pk_bf16(f1.z, f1.w));
        }
    } else {
        const int base = (bid - 6144) * 8;
        if (bid == 6144 && t == 0) *count = 0;
        if (t < 8) keys[base + t] = ~0ull;
        const int wave = t >> 6, lane = t & 63;
        const int row = base + wave * 2 + (lane >> 5);
        const int l = lane & 31, b = l >> 3, j = l & 7;
        const float* a = x + (size_t)row * D_DIM + b * 128 + j;
        float r = __fmul_rn(a[0], a[0]);
#pragma unroll
        for (int i = 1; i < 16; ++i) {
            const float v = a[i * 8];
            r = __fadd_rn(r, __fmul_rn(v, v));
        }
        r = __fadd_rn(r, __shfl_xor(r, 1));
        r = __fadd_rn(r, __shfl_xor(r, 2));
        r = __fadd_rn(r, __shfl_xor(r, 4));
        r = __fadd_rn(r, __shfl_xor(r, 8));
        r = __fadd_rn(r, __shfl_xor(r, 16));
        if (l == 0) sn[row] = r;
    }
}

// non-pre path: standalone sn+init (prepass skipped)
__global__ __launch_bounds__(256)
void vq_sn(const float* __restrict__ x, float* __restrict__ sn,
           u64* __restrict__ keys, int* __restrict__ count) {
    const int t = threadIdx.x;
    const int base = blockIdx.x * 8;
    if (blockIdx.x == 0 && t == 0) *count = 0;
    if (t < 8) keys[base + t] = ~0ull;
    const int wave = t >> 6, lane = t & 63;
    const int row = base + wave * 2 + (lane >> 5);
    const int l = lane & 31, b = l >> 3, j = l & 7;
    const float* a = x + (size_t)row * D_DIM + b * 128 + j;
    float r = __fmul_rn(a[0], a[0]);
#pragma unroll
    for (int i = 1; i < 16; ++i) {
        const float v = a[i * 8];
        r = __fadd_rn(r, __fmul_rn(v, v));
    }
    r = __fadd_rn(r, __shfl_xor(r, 1));
    r = __fadd_rn(r, __shfl_xor(r, 2));
    r = __fadd_rn(r, __shfl_xor(r, 4));
    r = __fadd_rn(r, __shfl_xor(r, 8));
    r = __fadd_rn(r, __shfl_xor(r, 16));
    if (l == 0) sn[row] = r;
}

// ---------------------------------------------------------------------------
// K1: screening GEMM. 128 rows x 256 codes, 4 waves of 64x128, single
// bf16-hi MFMA, XOR-swizzled LDS.
// PRE path (this round's change): direct async global->LDS staging via
// global_load_lds width=16. The XOR swizzle is applied on the per-lane
// GLOBAL source address (chunk = pos ^ ((row>>1)&3), a permutation within
// each contiguous 64B row-slab), LDS destination is linear — rule #21's
// "inverse-swz source + swz read" pattern. Read side (aoff/boff) unchanged
// => bit-identical MFMA inputs vs the reg-staged version.
// ---------------------------------------------------------------------------
template<bool PRE>
__global__ __launch_bounds__(256, 2)
void vq_screen2(const float* __restrict__ x, const float* __restrict__ cb,
                const ushort* __restrict__ xb, const ushort* __restrict__ cbb,
                float* __restrict__ g_dmax, uchar* __restrict__ g_cnt,
                uchar* __restrict__ g_cand) {
    __shared__ ushort Ash[128 * 32];
    __shared__ ushort Bsh[256 * 32];
    __shared__ unsigned vkey[128];
    __shared__ int ccnt[128];
    __shared__ uchar clist[128][CAP];

    const int t    = threadIdx.x;
    const int w    = t >> 6, lane = t & 63;
    const int fr   = lane & 15;
    const int quad = lane >> 4;
    const int wr   = (w & 1) * 64;
    const int wc   = (w >> 1) * 128;
    const int row0  = blockIdx.y * 128;
    const int kbase = blockIdx.x * 256;

    if (t < 128) { vkey[t] = 0u; ccnt[t] = 0; }

    int aoff[4], boff[8];
#pragma unroll
    for (int i = 0; i < 4; ++i) {
        const int rw = wr + i * 16 + fr;
        aoff[i] = rw * 32 + ((quad ^ (rw >> 1)) & 3) * 8;
    }
#pragma unroll
    for (int j = 0; j < 8; ++j) {
        const int rw = wc + j * 16 + fr;
        boff[j] = rw * 32 + ((quad ^ (rw >> 1)) & 3) * 8;
    }

    f32x4 acc[4][8];
#pragma unroll
    for (int i = 0; i < 4; ++i)
#pragma unroll
        for (int j = 0; j < 8; ++j) acc[i][j] = (f32x4)0.0f;

    if (PRE) {
        // per-lane pre-swizzled global sources; wave-uniform linear LDS dests
        const int la = lane >> 2;          // sub-row within 16-row group
        const int p  = lane & 3;           // 16B chunk position in LDS row
        const char* srcA0; const char* srcA1;
        const char* srcB0; const char* srcB1; const char* srcB2; const char* srcB3;
        ushort* dstA0; ushort* dstA1;
        ushort* dstB0; ushort* dstB1; ushort* dstB2; ushort* dstB3;
        {
            const int ia0 = w * 2 + 0, rA0 = ia0 * 16 + la;
            const int ia1 = w * 2 + 1, rA1 = ia1 * 16 + la;
            srcA0 = (const char*)xb + (size_t)(row0 + rA0) * 1024 + ((p ^ ((rA0 >> 1) & 3)) * 16);
            srcA1 = (const char*)xb + (size_t)(row0 + rA1) * 1024 + ((p ^ ((rA1 >> 1) & 3)) * 16);
            dstA0 = &Ash[ia0 * 512];
            dstA1 = &Ash[ia1 * 512];
            const int ib0 = w * 4 + 0, rB0 = ib0 * 16 + la;
            const int ib1 = w * 4 + 1, rB1 = ib1 * 16 + la;
            const int ib2 = w * 4 + 2, rB2 = ib2 * 16 + la;
            const int ib3 = w * 4 + 3, rB3 = ib3 * 16 + la;
            srcB0 = (const char*)cbb + (size_t)(kbase + rB0) * 1024 + ((p ^ ((rB0 >> 1) & 3)) * 16);
            srcB1 = (const char*)cbb + (size_t)(kbase + rB1) * 1024 + ((p ^ ((rB1 >> 1) & 3)) * 16);
            srcB2 = (const char*)cbb + (size_t)(kbase + rB2) * 1024 + ((p ^ ((rB2 >> 1) & 3)) * 16);
            srcB3 = (const char*)cbb + (size_t)(kbase + rB3) * 1024 + ((p ^ ((rB3 >> 1) & 3)) * 16);
            dstB0 = &Bsh[ib0 * 512];
            dstB1 = &Bsh[ib1 * 512];
            dstB2 = &Bsh[ib2 * 512];
            dstB3 = &Bsh[ib3 * 512];
        }
        for (int dc = 0; dc < 16; ++dc) {
            __syncthreads();               // all prior ds_reads done before overwrite
            gload_lds16(srcA0, dstA0);
            gload_lds16(srcA1, dstA1);
            gload_lds16(srcB0, dstB0);
            gload_lds16(srcB1, dstB1);
            gload_lds16(srcB2, dstB2);
            gload_lds16(srcB3, dstB3);
            srcA0 += 64; srcA1 += 64;
            srcB0 += 64; srcB1 += 64; srcB2 += 64; srcB3 += 64;
            __syncthreads();               // compiler drains vmcnt(0): slab landed
            bf16x8 af[4], bfv[8];
#pragma unroll
            for (int i = 0; i < 4; ++i) af[i] = *(const bf16x8*)&Ash[aoff[i]];
#pragma unroll
            for (int j = 0; j < 8; ++j) bfv[j] = *(const bf16x8*)&Bsh[boff[j]];
#pragma unroll
            for (int i = 0; i < 4; ++i)
#pragma unroll
                for (int j = 0; j < 8; ++j)
                    acc[i][j] = __builtin_amdgcn_mfma_f32_16x16x32_bf16(af[i], bfv[j], acc[i][j], 0, 0, 0);
        }
    } else {
        const int r = t >> 1, h = t & 1;
        const int sA = (r >> 1) & 3;
        const int ca0 = (2 * h) ^ sA;
        ushort* awp0 = &Ash[r * 32 + ca0 * 8];
        ushort* awp1 = &Ash[r * 32 + (ca0 ^ 1) * 8];
        const int sB = (t >> 1) & 3;
        ushort* bwp0 = &Bsh[t * 32 + (0 ^ sB) * 8];
        ushort* bwp1 = &Bsh[t * 32 + (1 ^ sB) * 8];
        ushort* bwp2 = &Bsh[t * 32 + (2 ^ sB) * 8];
        ushort* bwp3 = &Bsh[t * 32 + (3 ^ sB) * 8];
        const char* gA = (const char*)(x  + (size_t)(row0 + r) * D_DIM + h * 16);
        const char* gB = (const char*)(cb + (size_t)(kbase + t) * D_DIM);
        for (int dc = 0; dc < 16; ++dc) {
            const float4* fa = (const float4*)(gA + dc * 128);
            float4 f0 = fa[0], f1 = fa[1], f2 = fa[2], f3 = fa[3];
            uint4 a0 = make_uint4(pk_bf16(f0.x, f0.y), pk_bf16(f0.z, f0.w),
                                  pk_bf16(f1.x, f1.y), pk_bf16(f1.z, f1.w));
            uint4 a1 = make_uint4(pk_bf16(f2.x, f2.y), pk_bf16(f2.z, f2.w),
                                  pk_bf16(f3.x, f3.y), pk_bf16(f3.z, f3.w));
            const float4* fb = (const float4*)(gB + dc * 128);
            float4 g0 = fb[0], g1 = fb[1], g2 = fb[2], g3 = fb[3];
            float4 g4 = fb[4], g5 = fb[5], g6 = fb[6], g7 = fb[7];
            uint4 b0 = make_uint4(pk_bf16(g0.x, g0.y), pk_bf16(g0.z, g0.w),
                                  pk_bf16(g1.x, g1.y), pk_bf16(g1.z, g1.w));
            uint4 b1 = make_uint4(pk_bf16(g2.x, g2.y), pk_bf16(g2.z, g2.w),
                                  pk_bf16(g3.x, g3.y), pk_bf16(g3.z, g3.w));
            uint4 b2 = make_uint4(pk_bf16(g4.x, g4.y), pk_bf16(g4.z, g4.w),
                                  pk_bf16(g5.x, g5.y), pk_bf16(g5.z, g5.w));
            uint4 b3 = make_uint4(pk_bf16(g6.x, g6.y), pk_bf16(g6.z, g6.w),
                                  pk_bf16(g7.x, g7.y), pk_bf16(g7.z, g7.w));
            __syncthreads();
            *(uint4*)awp0 = a0; *(uint4*)awp1 = a1;
            *(uint4*)bwp0 = b0; *(uint4*)bwp1 = b1;
            *(uint4*)bwp2 = b2; *(uint4*)bwp3 = b3;
            __syncthreads();
            bf16x8 af[4], bfv[8];
#pragma unroll
            for (int i = 0; i < 4; ++i) af[i] = *(const bf16x8*)&Ash[aoff[i]];
#pragma unroll
            for (int j = 0; j < 8; ++j) bfv[j] = *(const bf16x8*)&Bsh[boff[j]];
#pragma unroll
            for (int i = 0; i < 4; ++i)
#pragma unroll
                for (int j = 0; j < 8; ++j)
                    acc[i][j] = __builtin_amdgcn_mfma_f32_16x16x32_bf16(af[i], bfv[j], acc[i][j], 0, 0, 0);
        }
    }

    __syncthreads();
#pragma unroll
    for (int i = 0; i < 4; ++i)
#pragma unroll
        for (int rg = 0; rg < 4; ++rg) {
            float m = acc[i][0][rg];
#pragma unroll
            for (int j = 1; j < 8; ++j) m = fmaxf(m, acc[i][j][rg]);
            m = fmaxf(m, __shfl_xor(m, 1));
            m = fmaxf(m, __shfl_xor(m, 2));
            m = fmaxf(m, __shfl_xor(m, 4));
            m = fmaxf(m, __shfl_xor(m, 8));
            if (fr == 0) atomicMax(&vkey[wr + i * 16 + quad * 4 + rg], fkey(m));
        }
    __syncthreads();
#pragma unroll
    for (int i = 0; i < 4; ++i)
#pragma unroll
        for (int rg = 0; rg < 4; ++rg) {
            const int row = wr + i * 16 + quad * 4 + rg;
            const float thr = finv(vkey[row]) - T2;
#pragma unroll
            for (int j = 0; j < 8; ++j) {
                if (acc[i][j][rg] >= thr) {
                    int p = atomicAdd(&ccnt[row], 1);
                    if (p < CAP) clist[row][p] = (uchar)(wc + j * 16 + fr);
                }
            }
        }
    __syncthreads();
    if (t < 128) {
        const size_t o = (size_t)(row0 + t) * NSPLIT + blockIdx.x;
        g_dmax[o] = finv(vkey[t]);
        int c = ccnt[t];
        g_cnt[o] = (uchar)(c > 255 ? 255 : c);
        ((uint2*)g_cand)[o] = *(const uint2*)clist[t];
    }
}

// ---------------------------------------------------------------------------
// K2: shortlist build, wave-aggregated list allocation (1 atomic per wave).
// ---------------------------------------------------------------------------
__global__ __launch_bounds__(256)
void vq_build(const float* __restrict__ g_dmax, const uchar* __restrict__ g_cnt,
              const uchar* __restrict__ g_cand, int2* __restrict__ list,
              int* __restrict__ count, float* __restrict__ idx_f) {
    const int row = blockIdx.x * blockDim.x + threadIdx.x;
    const int lane = threadIdx.x & 63;
    const float* dm = g_dmax + (size_t)row * NSPLIT;
    float g = dm[0];
#pragma unroll
    for (int s = 1; s < NSPLIT; ++s) g = fmaxf(g, dm[s]);
    const float thr = g - T2;

    int tot = 0, first = -1;
    for (int s = 0; s < NSPLIT; ++s) {
        if (dm[s] < thr) continue;
        const size_t o = (size_t)row * NSPLIT + s;
        const int c = g_cnt[o];
        tot += (c > CAP) ? 256 : c;
        if (first < 0) first = s * 256 + g_cand[o * CAP];
    }
    idx_f[row] = (float)first;   // final for tot==1; replay overrides otherwise

    const int need = (tot > 1) ? tot : 0;
    // wave inclusive prefix-sum of need
    int scan = need;
#pragma unroll
    for (int d = 1; d < 64; d <<= 1) {
        const int v = __shfl_up(scan, d, 64);
        if (lane >= d) scan += v;
    }
    const int wtot = __shfl(scan, 63, 64);
    int base = 0;
    if (lane == 63 && wtot > 0) base = atomicAdd(count, wtot);
    base = __shfl(base, 63, 64);
    if (need == 0) return;
    int pos = base + scan - need;

    for (int s = 0; s < NSPLIT; ++s) {
        if (dm[s] < thr) continue;
        const size_t o = (size_t)row * NSPLIT + s;
        const int c = g_cnt[o];
        if (c > CAP) {
            for (int u = 0; u < 256; ++u, ++pos)
                if (pos < LIST_CAP) list[pos] = make_int2(row, s * 256 + u);
        } else {
            for (int u = 0; u < c; ++u, ++pos)
                if (pos < LIST_CAP) list[pos] = make_int2(row, s * 256 + g_cand[o * CAP + u]);
        }
    }
}

// bit-exact numpy fp32 (baseline SSE3) einsum — validated absmax=0 (r2,r4-r6)
__device__ __forceinline__ float np_einsum_dot(const float* __restrict__ a,
                                               const float* __restrict__ b) {
    float S0 = 0.f, S1 = 0.f, S2 = 0.f, S3 = 0.f;
    for (int i = 0; i < D_DIM; i += 16) {
        S0 = __fadd_rn(S0, __fmul_rn(a[i + 12], b[i + 12]));
        S1 = __fadd_rn(S1, __fmul_rn(a[i + 13], b[i + 13]));
        S2 = __fadd_rn(S2, __fmul_rn(a[i + 14], b[i + 14]));
        S3 = __fadd_rn(S3, __fmul_rn(a[i + 15], b[i + 15]));
        S0 = __fadd_rn(S0, __fmul_rn(a[i +  8], b[i +  8]));
        S1 = __fadd_rn(S1, __fmul_rn(a[i +  9], b[i +  9]));
        S2 = __fadd_rn(S2, __fmul_rn(a[i + 10], b[i + 10]));
        S3 = __fadd_rn(S3, __fmul_rn(a[i + 11], b[i + 11]));
        S0 = __fadd_rn(S0, __fmul_rn(a[i +  4], b[i +  4]));
        S1 = __fadd_rn(S1, __fmul_rn(a[i +  5], b[i +  5]));
        S2 = __fadd_rn(S2, __fmul_rn(a[i +  6], b[i +  6]));
        S3 = __fadd_rn(S3, __fmul_rn(a[i +  7], b[i +  7]));
        S0 = __fadd_rn(S0, __fmul_rn(a[i +  0], b[i +  0]));
        S1 = __fadd_rn(S1, __fmul_rn(a[i +  1], b[i +  1]));
        S2 = __fadd_rn(S2, __fmul_rn(a[i +  2], b[i +  2]));
        S3 = __fadd_rn(S3, __fmul_rn(a[i +  3], b[i +  3]));
    }
    return __fadd_rn(__fadd_rn(S0, S1), __fadd_rn(S2, S3));
}

// ---------------------------------------------------------------------------
// K3: lane-per-entry exact replay; atomicMin on packed (distKey<<32)|k.
// ---------------------------------------------------------------------------
__global__ __launch_bounds__(256)
void vq_replay(const float* __restrict__ x, const float* __restrict__ cb,
               const float* __restrict__ sn, const int2* __restrict__ list,
               const int* __restrict__ count, u64* __restrict__ keys) {
    const int i = blockIdx.x * blockDim.x + threadIdx.x;
    int n = *count; if (n > LIST_CAP) n = LIST_CAP;
    if (i >= n) return;
    const int2 e = list[i];
    const float* zr = x + (size_t)e.x * D_DIM;
    const float d = __fadd_rn(sn[e.x],
                              __fmul_rn(-2.0f, np_einsum_dot(zr, cb + (size_t)e.y * D_DIM)));
    const u64 key = ((u64)fkey(d) << 32) | (unsigned)e.y;
    atomicMin(&keys[e.x], key);
}

// ---------------------------------------------------------------------------
// K4: resolve + gather z_q (exact fp32 straight-through) + per-row loss.
// ---------------------------------------------------------------------------
__global__ void vq_gather_kernel(const float* __restrict__ x,
                                 const float* __restrict__ cb,
                                 const u64* __restrict__ keys,
                                 float* __restrict__ idx_f,
                                 float* __restrict__ zq_out,
                                 double* __restrict__ psum) {
    const int row = blockIdx.x;
    const int t   = threadIdx.x;   // 128
    const u64 ky = keys[row];
    const int k = (ky != ~0ull) ? (int)(ky & 0xffffffffu) : (int)idx_f[row];
    const float4 c  = ((const float4*)(cb + (size_t)k   * D_DIM))[t];
    const float4 xv = ((const float4*)(x  + (size_t)row * D_DIM))[t];
    float4 o;
    o.x = __fadd_rn(xv.x, __fsub_rn(c.x, xv.x));
    o.y = __fadd_rn(xv.y, __fsub_rn(c.y, xv.y));
    o.z = __fadd_rn(xv.z, __fsub_rn(c.z, xv.z));
    o.w = __fadd_rn(xv.w, __fsub_rn(c.w, xv.w));
    ((float4*)(zq_out + (size_t)row * D_DIM))[t] = o;
    const double d0 = (double)c.x - (double)xv.x;
    const double d1 = (double)c.y - (double)xv.y;
    const double d2 = (double)c.z - (double)xv.z;
    const double d3 = (double)c.w - (double)xv.w;
    double s = d0 * d0 + d1 * d1 + d2 * d2 + d3 * d3;
#pragma unroll
    for (int off = 32; off > 0; off >>= 1) s += __shfl_xor(s, off, 64);
    __shared__ double red[2];
    if ((t & 63) == 0) red[t >> 6] = s;
    __syncthreads();
    if (t == 0) {
        psum[row] = red[0] + red[1];
        idx_f[row] = (float)k;
    }
}

__global__ void vq_finalize2(const double* __restrict__ psum,
                             float* __restrict__ losses) {
    __shared__ double red[4];
    const int t = threadIdx.x;   // 256
    double s = 0.0;
    for (int i = t; i < N_ROWS; i += 256) s += psum[i];
#pragma unroll
    for (int off = 32; off > 0; off >>= 1) s += __shfl_xor(s, off, 64);
    if ((t & 63) == 0) red[t >> 6] = s;
    __syncthreads();
    if (t == 0) {
        const double tot = red[0] + red[1] + red[2] + red[3];
        const float l = (float)(tot / (double)((size_t)N_ROWS * D_DIM));
        losses[0] = l;
        losses[1] = l;
    }
}

extern "C" void kernel_launch(void* const* d_in, const int* in_sizes, int n_in,
                              void* d_out, int out_size, void* d_ws, size_t ws_size,
                              hipStream_t stream) {
    const float* x  = (const float*)d_in[0];   // [16384, 512]
    const float* cb = (const float*)d_in[1];   // [8192, 512]
    float* out    = (float*)d_out;
    float* zq     = out;
    float* losses = out + (size_t)N_ROWS * D_DIM;
    float* idx_f  = losses + 2;
    char* ws = (char*)d_ws;

    const bool pre = (ws_size >= ((size_t)32 << 20));
    char* base = pre ? (ws + ((size_t)24 << 20)) : ws;

    // base layout (~7.3 MB):
    float*  g_dmax = (float*)(base);                     // 2048 KB
    uchar*  g_cnt  = (uchar*)(base + (2048u << 10));     //  512 KB
    uchar*  g_cand = (uchar*)(base + (2560u << 10));     // 4096 KB
    float*  sn     = (float*)(base + (6656u << 10));     //   64 KB
    u64*    keys   = (u64*)  (base + (6720u << 10));     //  128 KB
    int2*   list   = (int2*) (base + (6848u << 10));     //  256 KB
    int*    count  = (int*)  (base + (7104u << 10));     //   64 KB slot
    double* psum   = (double*)(base + (7168u << 10));    //  128 KB

    if (pre) {
        ushort* xb  = (ushort*)ws;                               // 16 MB
        ushort* cbb = (ushort*)(ws + ((size_t)16 << 20));        // 8 MB
        hipLaunchKernelGGL(vq_prepass, dim3(8192), dim3(256), 0, stream,
                           x, cb, (unsigned*)xb, (unsigned*)cbb, sn, keys, count);
        hipLaunchKernelGGL((vq_screen2<true>), dim3(K_CODES / 256, N_ROWS / 128), dim3(256), 0, stream,
                           x, cb, xb, cbb, g_dmax, g_cnt, g_cand);
    } else {
        hipLaunchKernelGGL(vq_sn, dim3(N_ROWS / 8), dim3(256), 0, stream,
                           x, sn, keys, count);
        hipLaunchKernelGGL((vq_screen2<false>), dim3(K_CODES / 256, N_ROWS / 128), dim3(256), 0, stream,
                           x, cb, (const ushort*)nullptr, (const ushort*)nullptr,
                           g_dmax, g_cnt, g_cand);
    }
    hipLaunchKernelGGL(vq_build, dim3(N_ROWS / 256), dim3(256), 0, stream,
                       g_dmax, g_cnt, g_cand, list, count, idx_f);
    hipLaunchKernelGGL(vq_replay, dim3(LIST_CAP / 256), dim3(256), 0, stream,
                       x, cb, sn, list, count, keys);
    hipLaunchKernelGGL(vq_gather_kernel, dim3(N_ROWS), dim3(128), 0, stream,
                       x, cb, keys, idx_f, zq, psum);
    hipLaunchKernelGGL(vq_finalize2, dim3(1), dim3(256), 0, stream,
                       psum, losses);
}